// Round 3
// baseline (517.607 us; speedup 1.0000x reference)
//
#include <hip/hip_runtime.h>
#include <cstdint>
#include <cstddef>

#define B_ 2
#define T_ 2048
#define D_ 2048
#define H_ 16
#define HD_ 128
#define EPS_ 1e-6f
#define QSCALE_ 0.08838834764831845f  // 1/sqrt(128)
#define KVSTRIDE_ (H_ * HD_)          // 2048 elems between consecutive t

typedef unsigned short u16;
typedef short s16x8 __attribute__((ext_vector_type(8)));
typedef float f32x4 __attribute__((ext_vector_type(4)));

__device__ __forceinline__ float bf2f(u16 h) {
  union { unsigned int u; float f; } v;
  v.u = ((unsigned int)h) << 16;
  return v.f;
}
__device__ __forceinline__ u16 f2bf(float f) {
  union { float f; unsigned int u; } v;
  v.f = f;
  unsigned int r = v.u + 0x7FFFu + ((v.u >> 16) & 1u);  // round-to-nearest-even
  return (u16)(r >> 16);
}

// async global->LDS, 16B per lane (LDS dest = wave-uniform base + lane*16)
__device__ __forceinline__ void gload16(const void* g, void* l) {
  __builtin_amdgcn_global_load_lds(
      (const __attribute__((address_space(1))) unsigned int*)g,
      (__attribute__((address_space(3))) unsigned int*)l, 16, 0, 0);
}

// ---------------- fp32 -> bf16 cast, all 5 tensors in one dispatch ----------------
// regions: [0]=x (8192 blocks), [1..4]=Wq,Wk,Wv,Wo (4096 blocks each)
__global__ void cvt_all(const float* __restrict__ x, const float* __restrict__ wq,
                        const float* __restrict__ wk, const float* __restrict__ wv,
                        const float* __restrict__ wo, u16* __restrict__ xb,
                        u16* __restrict__ wqb, u16* __restrict__ wkb,
                        u16* __restrict__ wvb, u16* __restrict__ wob) {
  int bid = blockIdx.x;
  const float* in;
  u16* out;
  int i;
  if (bid < 8192) {
    in = x; out = xb; i = bid * 256 + threadIdx.x;
  } else {
    int r = (bid - 8192) >> 12;          // 0..3
    int wb = (bid - 8192) & 4095;
    const float* ins[4] = {wq, wk, wv, wo};
    u16* outs[4] = {wqb, wkb, wvb, wob};
    in = ins[r]; out = outs[r]; i = wb * 256 + threadIdx.x;
  }
  float4 v = ((const float4*)in)[i];
  ((ushort4*)out)[i] = make_ushort4(f2bf(v.x), f2bf(v.y), f2bf(v.z), f2bf(v.w));
}

// ---------------- fused QKV GEMM (z-indexed), m97 structure ----------------
// z=0: Q = x * Wq^T  (M=4096,N=2048); z=1: K = x * Wk^T; z=2: Vt = Wv * x^T (M=2048,N=4096)
__global__ __launch_bounds__(256, 2) void gemm_qkv(const u16* __restrict__ xb,
                                                   const u16* __restrict__ wq,
                                                   const u16* __restrict__ wk,
                                                   const u16* __restrict__ wv,
                                                   u16* __restrict__ qo,
                                                   u16* __restrict__ ko,
                                                   u16* __restrict__ vo) {
  const u16 *A, *Bm;
  u16* C;
  int M, N;
  if (blockIdx.z == 0)      { A = xb; Bm = wq; C = qo; M = 4096; N = 2048; }
  else if (blockIdx.z == 1) { A = xb; Bm = wk; C = ko; M = 4096; N = 2048; }
  else                      { A = wv; Bm = xb; C = vo; M = 2048; N = 4096; }
  const int m0 = blockIdx.y * 128, n0 = blockIdx.x * 128;
  if (m0 >= M || n0 >= N) return;
  const int K = 2048;

  __shared__ u16 As[128 * 32];
  __shared__ u16 Bs[128 * 32];
  const int tid = threadIdx.x;
  const int w = tid >> 6, lane = tid & 63, quad = lane >> 4, c = lane & 15;
  const int wm = w & 1, wn = w >> 1;

  f32x4 acc[4][4];
#pragma unroll
  for (int i = 0; i < 4; ++i)
#pragma unroll
    for (int j = 0; j < 4; ++j) acc[i][j] = (f32x4){0.f, 0.f, 0.f, 0.f};

  for (int k0 = 0; k0 < K; k0 += 32) {
    __syncthreads();
#pragma unroll
    for (int i = 0; i < 2; ++i) {
      int chunk = (w * 2 + i) * 64 + lane;  // 0..511
      int row = chunk >> 2, cc = chunk & 3;
      gload16(A + (size_t)(m0 + row) * K + k0 + cc * 8, (void*)(As + chunk * 8));
      gload16(Bm + (size_t)(n0 + row) * K + k0 + cc * 8, (void*)(Bs + chunk * 8));
    }
    __syncthreads();
    s16x8 af[4], bf[4];
#pragma unroll
    for (int mi = 0; mi < 4; ++mi)
      af[mi] = *(const s16x8*)(As + (wm * 64 + mi * 16 + c) * 32 + quad * 8);
#pragma unroll
    for (int ni = 0; ni < 4; ++ni)
      bf[ni] = *(const s16x8*)(Bs + (wn * 64 + ni * 16 + c) * 32 + quad * 8);
#pragma unroll
    for (int mi = 0; mi < 4; ++mi)
#pragma unroll
      for (int ni = 0; ni < 4; ++ni)
        acc[mi][ni] = __builtin_amdgcn_mfma_f32_16x16x32_bf16(af[mi], bf[ni], acc[mi][ni], 0, 0, 0);
  }

#pragma unroll
  for (int mi = 0; mi < 4; ++mi)
#pragma unroll
    for (int ni = 0; ni < 4; ++ni)
#pragma unroll
      for (int r = 0; r < 4; ++r) {
        int row = m0 + wm * 64 + mi * 16 + quad * 4 + r;
        int col = n0 + wn * 64 + ni * 16 + c;
        C[(size_t)row * N + col] = f2bf(acc[mi][ni][r]);
      }
}

// ---------------- standalone GEMM for the output projection (f32 out) ----------------
__global__ __launch_bounds__(256, 2) void gemm_out(const u16* __restrict__ A,
                                                   const u16* __restrict__ Bm,
                                                   float* __restrict__ Cout,
                                                   int M, int N, int K) {
  __shared__ u16 As[128 * 32];
  __shared__ u16 Bs[128 * 32];
  const int tid = threadIdx.x;
  const int w = tid >> 6, lane = tid & 63, quad = lane >> 4, c = lane & 15;
  const int wm = w & 1, wn = w >> 1;
  const int m0 = blockIdx.y * 128, n0 = blockIdx.x * 128;

  f32x4 acc[4][4];
#pragma unroll
  for (int i = 0; i < 4; ++i)
#pragma unroll
    for (int j = 0; j < 4; ++j) acc[i][j] = (f32x4){0.f, 0.f, 0.f, 0.f};

  for (int k0 = 0; k0 < K; k0 += 32) {
    __syncthreads();
#pragma unroll
    for (int i = 0; i < 2; ++i) {
      int chunk = (w * 2 + i) * 64 + lane;
      int row = chunk >> 2, cc = chunk & 3;
      gload16(A + (size_t)(m0 + row) * K + k0 + cc * 8, (void*)(As + chunk * 8));
      gload16(Bm + (size_t)(n0 + row) * K + k0 + cc * 8, (void*)(Bs + chunk * 8));
    }
    __syncthreads();
    s16x8 af[4], bf[4];
#pragma unroll
    for (int mi = 0; mi < 4; ++mi)
      af[mi] = *(const s16x8*)(As + (wm * 64 + mi * 16 + c) * 32 + quad * 8);
#pragma unroll
    for (int ni = 0; ni < 4; ++ni)
      bf[ni] = *(const s16x8*)(Bs + (wn * 64 + ni * 16 + c) * 32 + quad * 8);
#pragma unroll
    for (int mi = 0; mi < 4; ++mi)
#pragma unroll
      for (int ni = 0; ni < 4; ++ni)
        acc[mi][ni] = __builtin_amdgcn_mfma_f32_16x16x32_bf16(af[mi], bf[ni], acc[mi][ni], 0, 0, 0);
  }

#pragma unroll
  for (int mi = 0; mi < 4; ++mi)
#pragma unroll
    for (int ni = 0; ni < 4; ++ni)
#pragma unroll
      for (int r = 0; r < 4; ++r) {
        int row = m0 + wm * 64 + mi * 16 + quad * 4 + r;
        int col = n0 + wn * 64 + ni * 16 + c;
        Cout[(size_t)row * N + col] = acc[mi][ni][r];
      }
}

// ---------------- fused RMSNorm + interleaved RoPE, q and k in one dispatch ----------------
__global__ void rmsnorm_rope2(u16* __restrict__ qx, u16* __restrict__ kx,
                              const float* __restrict__ qw, const float* __restrict__ kw) {
  u16* x = blockIdx.y ? kx : qx;
  const float* nw = blockIdx.y ? kw : qw;
  const float outscale = blockIdx.y ? 1.0f : QSCALE_;
  const int tid = threadIdx.x;
  const int w = tid >> 6, lane = tid & 63;
  const int vec = blockIdx.x * 4 + w;   // (b*T + t)*H + h
  const int t = (vec >> 4) & (T_ - 1);  // /H % T
  u16* base = x + (size_t)vec * HD_;
  unsigned int pk = *(const unsigned int*)(base + lane * 2);
  float e = bf2f((u16)(pk & 0xFFFFu));
  float o = bf2f((u16)(pk >> 16));
  float ss = e * e + o * o;
#pragma unroll
  for (int off = 1; off < 64; off <<= 1) ss += __shfl_xor(ss, off, 64);
  float rn = rsqrtf(ss * (1.0f / HD_) + EPS_);
  float we = nw[lane * 2], wo = nw[lane * 2 + 1];
  e = e * rn * we;
  o = o * rn * wo;
  float freq = expf(-(float)lane * (9.210340371976184f / 64.0f));  // 10000^(-lane/64)
  float ang = (float)t * freq;
  float sn, cs;
  sincosf(ang, &sn, &cs);
  float re = (e * cs - o * sn) * outscale;
  float ro = (e * sn + o * cs) * outscale;
  *(unsigned int*)(base + lane * 2) = ((unsigned int)f2bf(ro) << 16) | (unsigned int)f2bf(re);
}

// ---------------- causal flash attention, Br=128 / Bc=64, bf16 MFMA ----------------
// Q scaled by 1/sqrt(HD), layout (B,T,H,HD). K layout (B,T,H,HD).
// V TRANSPOSED: Vt[o=h*128+d][tok=b*2048+t]. K/Vt staged via global_load_lds with
// XOR-swizzle on the GLOBAL side (LDS dest must be lane-ordered): LDS[row][slot]
// holds global chunk slot^(row&7); fragment reads land 2-way (free) on banks.
__global__ __launch_bounds__(256) void attn_fwd(const u16* __restrict__ Q,
                                                const u16* __restrict__ Kg,
                                                const u16* __restrict__ Vt,
                                                u16* __restrict__ O) {
  __shared__ u16 Ks[64 * 128];    // swizzled, unpadded
  __shared__ u16 Vts[128 * 64];   // swizzled, unpadded
  __shared__ u16 Ps[128 * 72];    // +8 pad, wave-private row ranges
  const int tid = threadIdx.x;
  const int w = tid >> 6, lane = tid & 63, quad = lane >> 4, c = lane & 15;
  const int bid = blockIdx.x;
  // 512 blocks, all co-resident at 2/CU. Pair bid and bid+256 with complementary
  // qb so per-CU work is constant (iter counts sum to 34) under round-robin fill.
  int qb, hb;
  if (bid < 256) { qb = 15 - ((bid >> 5) & 7); hb = bid & 31; }
  else           { qb = (bid >> 5) & 7;        hb = bid & 31; }
  const int h = hb & 15, b = hb >> 4;
  const int q0 = qb * 128;
  const int jmax = 2 * qb + 1;

  // Q fragments in registers: rows q0 + w*32 + mi*16 + c (A-layout)
  s16x8 qf[2][4];
#pragma unroll
  for (int mi = 0; mi < 2; ++mi) {
    const u16* qbase = Q + ((size_t)(b * T_ + q0 + w * 32 + mi * 16 + c) * H_ + h) * HD_;
#pragma unroll
    for (int kk = 0; kk < 4; ++kk) qf[mi][kk] = *(const s16x8*)(qbase + kk * 32 + quad * 8);
  }

  f32x4 of[2][8];
#pragma unroll
  for (int mi = 0; mi < 2; ++mi)
#pragma unroll
    for (int ot = 0; ot < 8; ++ot) of[mi][ot] = (f32x4){0.f, 0.f, 0.f, 0.f};
  float m_i[2][4], l_i[2][4];
#pragma unroll
  for (int mi = 0; mi < 2; ++mi)
#pragma unroll
    for (int r = 0; r < 4; ++r) { m_i[mi][r] = -1e30f; l_i[mi][r] = 0.f; }

  const u16* kbase = Kg + ((size_t)b * T_ * H_ + h) * HD_;
  const u16* vtbase = Vt + (size_t)(h * HD_) * (B_ * T_) + (size_t)b * T_;

  for (int j = 0; j <= jmax; ++j) {
    __syncthreads();
    const u16* krow = kbase + (size_t)(j * 64) * KVSTRIDE_;
    const u16* vrow = vtbase + j * 64;
#pragma unroll
    for (int i = 0; i < 4; ++i) {
      int chunk = i * 256 + tid;               // 0..1023
      int kr = chunk >> 4, kc = chunk & 15;    // K: 64 rows x 16 chunks
      gload16(krow + (size_t)kr * KVSTRIDE_ + (size_t)((kc ^ (kr & 7)) * 8),
              (void*)(Ks + chunk * 8));
      int vr = chunk >> 3, vc = chunk & 7;     // Vt: 128 rows x 8 chunks
      gload16(vrow + (size_t)vr * (B_ * T_) + (size_t)((vc ^ (vr & 7)) * 8),
              (void*)(Vts + chunk * 8));
    }
    __syncthreads();

    // S = Q K^T : sf[mi][ni], K-frags read once per (ni,kk), reused across mi
    f32x4 sf[2][4];
#pragma unroll
    for (int ni = 0; ni < 4; ++ni) {
      s16x8 kf[4];
#pragma unroll
      for (int kk = 0; kk < 4; ++kk)
        kf[kk] = *(const s16x8*)(Ks + (ni * 16 + c) * 128 + (((kk * 4 + quad) ^ (c & 7)) * 8));
#pragma unroll
      for (int mi = 0; mi < 2; ++mi) {
        f32x4 a = (f32x4){0.f, 0.f, 0.f, 0.f};
#pragma unroll
        for (int kk = 0; kk < 4; ++kk)
          a = __builtin_amdgcn_mfma_f32_16x16x32_bf16(qf[mi][kk], kf[kk], a, 0, 0, 0);
        sf[mi][ni] = a;
      }
    }
    // causal mask: rows of this wave start at q0+w*32; tile cols end at (j+1)*64-1
    if ((j + 1) * 64 > q0 + w * 32) {
#pragma unroll
      for (int mi = 0; mi < 2; ++mi)
#pragma unroll
        for (int ni = 0; ni < 4; ++ni)
#pragma unroll
          for (int r = 0; r < 4; ++r) {
            int rowg = q0 + w * 32 + mi * 16 + quad * 4 + r;
            int colg = j * 64 + ni * 16 + c;
            if (colg > rowg) sf[mi][ni][r] = -1e30f;
          }
    }
    // online softmax (rows live across 16 lanes sharing quad)
#pragma unroll
    for (int mi = 0; mi < 2; ++mi) {
      float mc[4];
#pragma unroll
      for (int r = 0; r < 4; ++r)
        mc[r] = fmaxf(fmaxf(sf[mi][0][r], sf[mi][1][r]), fmaxf(sf[mi][2][r], sf[mi][3][r]));
#pragma unroll
      for (int off = 1; off < 16; off <<= 1)
#pragma unroll
        for (int r = 0; r < 4; ++r) mc[r] = fmaxf(mc[r], __shfl_xor(mc[r], off, 64));
#pragma unroll
      for (int r = 0; r < 4; ++r) {
        float mnew = fmaxf(m_i[mi][r], mc[r]);
        float alpha = __expf(m_i[mi][r] - mnew);
        m_i[mi][r] = mnew;
        l_i[mi][r] *= alpha;
#pragma unroll
        for (int ot = 0; ot < 8; ++ot) of[mi][ot][r] *= alpha;
      }
      float rs[4] = {0.f, 0.f, 0.f, 0.f};
#pragma unroll
      for (int ni = 0; ni < 4; ++ni)
#pragma unroll
        for (int r = 0; r < 4; ++r) {
          float p = __expf(sf[mi][ni][r] - m_i[mi][r]);
          sf[mi][ni][r] = p;
          rs[r] += p;
        }
#pragma unroll
      for (int off = 1; off < 16; off <<= 1)
#pragma unroll
        for (int r = 0; r < 4; ++r) rs[r] += __shfl_xor(rs[r], off, 64);
#pragma unroll
      for (int r = 0; r < 4; ++r) l_i[mi][r] += rs[r];
      // P write: wave-private rows, no barrier needed before read-back
#pragma unroll
      for (int ni = 0; ni < 4; ++ni)
#pragma unroll
        for (int r = 0; r < 4; ++r)
          Ps[(w * 32 + mi * 16 + quad * 4 + r) * 72 + ni * 16 + c] = f2bf(sf[mi][ni][r]);
    }
    // O += P V : P A-frags (own rows), V B-frags read once per (ot,kk), reused across mi
    s16x8 pa[2][2];
#pragma unroll
    for (int mi = 0; mi < 2; ++mi)
#pragma unroll
      for (int kk = 0; kk < 2; ++kk)
        pa[mi][kk] = *(const s16x8*)(Ps + (w * 32 + mi * 16 + c) * 72 + kk * 32 + quad * 8);
#pragma unroll
    for (int ot = 0; ot < 8; ++ot) {
      s16x8 vf[2];
#pragma unroll
      for (int kk = 0; kk < 2; ++kk)
        vf[kk] = *(const s16x8*)(Vts + (ot * 16 + c) * 64 + (((kk * 4 + quad) ^ (c & 7)) * 8));
#pragma unroll
      for (int mi = 0; mi < 2; ++mi)
#pragma unroll
        for (int kk = 0; kk < 2; ++kk)
          of[mi][ot] = __builtin_amdgcn_mfma_f32_16x16x32_bf16(pa[mi][kk], vf[kk], of[mi][ot], 0, 0, 0);
    }
  }

  // epilogue: O /= l, store bf16 ctx (flat (B,T,H,HD) layout)
  u16* obase = O + ((size_t)(b * T_ + q0 + w * 32) * H_ + h) * HD_;
#pragma unroll
  for (int mi = 0; mi < 2; ++mi) {
    float inv[4];
#pragma unroll
    for (int r = 0; r < 4; ++r) inv[r] = 1.0f / l_i[mi][r];
#pragma unroll
    for (int ot = 0; ot < 8; ++ot)
#pragma unroll
      for (int r = 0; r < 4; ++r)
        obase[(size_t)(mi * 16 + quad * 4 + r) * KVSTRIDE_ + ot * 16 + c] =
            f2bf(of[mi][ot][r] * inv[r]);
  }
}

// ---------------- launch ----------------
extern "C" void kernel_launch(void* const* d_in, const int* in_sizes, int n_in,
                              void* d_out, int out_size, void* d_ws, size_t ws_size,
                              hipStream_t stream) {
  const float* x = (const float*)d_in[0];
  const float* Wq = (const float*)d_in[1];
  const float* Wk = (const float*)d_in[2];
  const float* Wv = (const float*)d_in[3];
  const float* Wo = (const float*)d_in[4];
  const float* qw = (const float*)d_in[5];
  const float* kw = (const float*)d_in[6];
  float* out = (float*)d_out;

  const size_t xE = (size_t)B_ * T_ * D_;   // 8388608
  const size_t wE = (size_t)D_ * H_ * HD_;  // 4194304
  const size_t need = xE * 2 * 5 + wE * 2 * 4;  // ~112 MB
  if (ws_size < need) return;

  char* ws = (char*)d_ws;
  u16* xb = (u16*)ws;   ws += xE * 2;
  u16* wqb = (u16*)ws;  ws += wE * 2;
  u16* wkb = (u16*)ws;  ws += wE * 2;
  u16* wvb = (u16*)ws;  ws += wE * 2;
  u16* wob = (u16*)ws;  ws += wE * 2;
  u16* qb = (u16*)ws;   ws += xE * 2;
  u16* kb = (u16*)ws;   ws += xE * 2;
  u16* vtb = (u16*)ws;  ws += xE * 2;   // V^T: [H*HD][B*T]
  u16* ctxb = (u16*)ws; ws += xE * 2;

  cvt_all<<<8192 + 4 * 4096, 256, 0, stream>>>(x, Wq, Wk, Wv, Wo, xb, wqb, wkb, wvb, wob);

  gemm_qkv<<<dim3(32, 32, 3), 256, 0, stream>>>(xb, wqb, wkb, wvb, qb, kb, vtb);

  rmsnorm_rope2<<<dim3(16384, 2), 256, 0, stream>>>(qb, kb, qw, kw);

  attn_fwd<<<512, 256, 0, stream>>>(qb, kb, vtb, ctxb);

  gemm_out<<<dim3(16, 32), 256, 0, stream>>>(ctxb, wob, out, 4096, 2048, 2048);
}

// Round 4
// 489.141 us; speedup vs baseline: 1.0582x; 1.0582x over previous
//
#include <hip/hip_runtime.h>
#include <cstdint>
#include <cstddef>

#define B_ 2
#define T_ 2048
#define D_ 2048
#define H_ 16
#define HD_ 128
#define EPS_ 1e-6f
#define QSCALE_ 0.08838834764831845f  // 1/sqrt(128)
#define KVSTRIDE_ (H_ * HD_)          // 2048 elems between consecutive t

typedef unsigned short u16;
typedef short s16x8 __attribute__((ext_vector_type(8)));
typedef float f32x4 __attribute__((ext_vector_type(4)));

__device__ __forceinline__ float bf2f(u16 h) {
  union { unsigned int u; float f; } v;
  v.u = ((unsigned int)h) << 16;
  return v.f;
}
__device__ __forceinline__ u16 f2bf(float f) {
  union { float f; unsigned int u; } v;
  v.f = f;
  unsigned int r = v.u + 0x7FFFu + ((v.u >> 16) & 1u);  // round-to-nearest-even
  return (u16)(r >> 16);
}

// async global->LDS, 16B per lane (LDS dest = wave-uniform base + lane*16)
__device__ __forceinline__ void gload16(const void* g, void* l) {
  __builtin_amdgcn_global_load_lds(
      (const __attribute__((address_space(1))) unsigned int*)g,
      (__attribute__((address_space(3))) unsigned int*)l, 16, 0, 0);
}

// ---------------- fp32 -> bf16 cast ----------------
__global__ void cvt_f32_bf16(const float* __restrict__ in, u16* __restrict__ out, int n4) {
  int i = blockIdx.x * blockDim.x + threadIdx.x;
  if (i < n4) {
    float4 v = ((const float4*)in)[i];
    ((ushort4*)out)[i] = make_ushort4(f2bf(v.x), f2bf(v.y), f2bf(v.z), f2bf(v.w));
  }
}

// ---------------- bf16 GEMM: C[M,N] = A[M,K] * Bm[N,K]^T (m97 structure) ----------------
template <int OUT_BF16>
__global__ __launch_bounds__(256, 2) void gemm_btn(const u16* __restrict__ A,
                                                   const u16* __restrict__ Bm,
                                                   void* __restrict__ Cout,
                                                   int M, int N, int K) {
  __shared__ u16 As[128 * 32];
  __shared__ u16 Bs[128 * 32];
  const int tid = threadIdx.x;
  const int w = tid >> 6, lane = tid & 63, quad = lane >> 4, c = lane & 15;
  const int wm = w & 1, wn = w >> 1;
  const int m0 = blockIdx.y * 128, n0 = blockIdx.x * 128;

  f32x4 acc[4][4];
#pragma unroll
  for (int i = 0; i < 4; ++i)
#pragma unroll
    for (int j = 0; j < 4; ++j) acc[i][j] = (f32x4){0.f, 0.f, 0.f, 0.f};

  for (int k0 = 0; k0 < K; k0 += 32) {
    __syncthreads();
#pragma unroll
    for (int i = 0; i < 2; ++i) {
      int chunk = (w * 2 + i) * 64 + lane;  // 0..511
      int row = chunk >> 2, cc = chunk & 3;
      gload16(A + (size_t)(m0 + row) * K + k0 + cc * 8, (void*)(As + chunk * 8));
      gload16(Bm + (size_t)(n0 + row) * K + k0 + cc * 8, (void*)(Bs + chunk * 8));
    }
    __syncthreads();
    s16x8 af[4], bf[4];
#pragma unroll
    for (int mi = 0; mi < 4; ++mi)
      af[mi] = *(const s16x8*)(As + (wm * 64 + mi * 16 + c) * 32 + quad * 8);
#pragma unroll
    for (int ni = 0; ni < 4; ++ni)
      bf[ni] = *(const s16x8*)(Bs + (wn * 64 + ni * 16 + c) * 32 + quad * 8);
#pragma unroll
    for (int mi = 0; mi < 4; ++mi)
#pragma unroll
      for (int ni = 0; ni < 4; ++ni)
        acc[mi][ni] = __builtin_amdgcn_mfma_f32_16x16x32_bf16(af[mi], bf[ni], acc[mi][ni], 0, 0, 0);
  }

#pragma unroll
  for (int mi = 0; mi < 4; ++mi)
#pragma unroll
    for (int ni = 0; ni < 4; ++ni)
#pragma unroll
      for (int r = 0; r < 4; ++r) {
        int row = m0 + wm * 64 + mi * 16 + quad * 4 + r;
        int col = n0 + wn * 64 + ni * 16 + c;
        float v = acc[mi][ni][r];
        if (OUT_BF16)
          ((u16*)Cout)[(size_t)row * N + col] = f2bf(v);
        else
          ((float*)Cout)[(size_t)row * N + col] = v;
      }
}

// ---------------- fused RMSNorm + interleaved RoPE (in-place on bf16) ----------------
__global__ void rmsnorm_rope(u16* __restrict__ x, const float* __restrict__ nw, float outscale) {
  const int tid = threadIdx.x;
  const int w = tid >> 6, lane = tid & 63;
  const int vec = blockIdx.x * 4 + w;   // (b*T + t)*H + h
  const int t = (vec >> 4) & (T_ - 1);  // /H % T
  u16* base = x + (size_t)vec * HD_;
  unsigned int pk = *(const unsigned int*)(base + lane * 2);
  float e = bf2f((u16)(pk & 0xFFFFu));
  float o = bf2f((u16)(pk >> 16));
  float ss = e * e + o * o;
#pragma unroll
  for (int off = 1; off < 64; off <<= 1) ss += __shfl_xor(ss, off, 64);
  float rn = rsqrtf(ss * (1.0f / HD_) + EPS_);
  float we = nw[lane * 2], wo = nw[lane * 2 + 1];
  e = e * rn * we;
  o = o * rn * wo;
  float freq = expf(-(float)lane * (9.210340371976184f / 64.0f));  // 10000^(-lane/64)
  float ang = (float)t * freq;
  float sn, cs;
  sincosf(ang, &sn, &cs);
  float re = (e * cs - o * sn) * outscale;
  float ro = (e * sn + o * cs) * outscale;
  *(unsigned int*)(base + lane * 2) = ((unsigned int)f2bf(ro) << 16) | (unsigned int)f2bf(re);
}

// ---------------- causal flash attention: barrier-free, static-max softmax ----------------
// Q scaled by 1/sqrt(HD): after RMS-norm ||q_row||=1, ||k_row||=sqrt(128) -> |S| <= 11.32.
// Static max m=12: p = exp(S-12), l = plain sum (deferred reduction). No running max,
// no in-loop shuffles, no in-loop barriers.
// Wave (jp, rh): rows rh*32..+31, KV-tiles j = jp, jp+2, ... K/V/Q fragments loaded
// DIRECTLY from global (16B contiguous per lane); LDS only for the wave-private P
// round-trip and the epilogue jp-merge.
__global__ __launch_bounds__(256, 2) void attn_fwd(const u16* __restrict__ Q,
                                                   const u16* __restrict__ Kg,
                                                   const u16* __restrict__ Vt,
                                                   u16* __restrict__ O) {
  __shared__ __attribute__((aligned(16))) char smem[33024];
  const int tid = threadIdx.x;
  const int w = tid >> 6, lane = tid & 63, quad = lane >> 4, c = lane & 15;
  const int jp = w & 1, rh = w >> 1;
  const int bid = blockIdx.x;
  const int bh = bid & 31;          // same (b,h) -> same bid%8 -> same XCD slot
  const int qt = 31 - (bid >> 5);   // heavy q-tiles dispatch first
  const int h = bh & 15, b = bh >> 4;
  const int q0 = qt * 64;

  u16* Pw = (u16*)(smem + w * 4608);  // per-wave P: 32 rows x 72 (pad 8)
  float* Mb = (float*)smem;           // epilogue merge: rh*4096 floats; l at 8192

  // Q A-frags: rows q0 + rh*32 + mi*16 + c (loop-invariant, registers)
  s16x8 qf[2][4];
#pragma unroll
  for (int mi = 0; mi < 2; ++mi) {
    const u16* qb = Q + ((size_t)(b * T_ + q0 + rh * 32 + mi * 16 + c) * H_ + h) * HD_;
#pragma unroll
    for (int kk = 0; kk < 4; ++kk) qf[mi][kk] = *(const s16x8*)(qb + kk * 32 + quad * 8);
  }

  f32x4 of[2][8];
#pragma unroll
  for (int mi = 0; mi < 2; ++mi)
#pragma unroll
    for (int ot = 0; ot < 8; ++ot) of[mi][ot] = (f32x4){0.f, 0.f, 0.f, 0.f};
  f32x4 l4[2] = {(f32x4){0.f, 0.f, 0.f, 0.f}, (f32x4){0.f, 0.f, 0.f, 0.f}};

  const u16* kbase = Kg + ((size_t)b * T_ * H_ + h) * HD_;
  const u16* vtbase = Vt + (size_t)(h * HD_) * (B_ * T_) + (size_t)b * T_;

  for (int j = jp; j <= qt; j += 2) {
    // ---- S = Q K^T : K B-frags direct from global (16 rows x 64B, L1/L2-served) ----
    f32x4 sf[2][4];
    const u16* krow = kbase + (size_t)(j * 64) * KVSTRIDE_;
#pragma unroll
    for (int ni = 0; ni < 4; ++ni) {
      s16x8 kf[4];
      const u16* ka = krow + (size_t)(ni * 16 + c) * KVSTRIDE_;
#pragma unroll
      for (int kk = 0; kk < 4; ++kk) kf[kk] = *(const s16x8*)(ka + kk * 32 + quad * 8);
#pragma unroll
      for (int mi = 0; mi < 2; ++mi) {
        f32x4 a = (f32x4){0.f, 0.f, 0.f, 0.f};
#pragma unroll
        for (int kk = 0; kk < 4; ++kk)
          a = __builtin_amdgcn_mfma_f32_16x16x32_bf16(qf[mi][kk], kf[kk], a, 0, 0, 0);
        sf[mi][ni] = a;
      }
    }
    // causal mask on the diagonal tile (handled by the jp == qt&1 wave)
    if (j == qt) {
#pragma unroll
      for (int mi = 0; mi < 2; ++mi)
#pragma unroll
        for (int ni = 0; ni < 4; ++ni)
#pragma unroll
          for (int r = 0; r < 4; ++r) {
            int rowg = rh * 32 + mi * 16 + quad * 4 + r;  // relative to q0
            int colg = ni * 16 + c;                       // relative to j*64 == q0
            if (colg > rowg) sf[mi][ni][r] = -1e30f;
          }
    }
    // ---- static-max softmax: p = exp(S-12); accumulate per-lane partial l; P->LDS ----
#pragma unroll
    for (int mi = 0; mi < 2; ++mi)
#pragma unroll
      for (int ni = 0; ni < 4; ++ni)
#pragma unroll
        for (int r = 0; r < 4; ++r) {
          float p = __expf(sf[mi][ni][r] - 12.0f);
          l4[mi][r] += p;
          Pw[(mi * 16 + quad * 4 + r) * 72 + ni * 16 + c] = f2bf(p);
        }
    // ---- O += P V : P A-frags (wave-private LDS, in-wave ordering via lgkmcnt), ----
    // ---- V B-frags direct from global Vt (16B contiguous per lane)              ----
    s16x8 pa[2][2];
#pragma unroll
    for (int mi = 0; mi < 2; ++mi)
#pragma unroll
      for (int kk = 0; kk < 2; ++kk)
        pa[mi][kk] = *(const s16x8*)(Pw + (mi * 16 + c) * 72 + kk * 32 + quad * 8);
    const u16* vrow = vtbase + j * 64;
#pragma unroll
    for (int ot = 0; ot < 8; ++ot) {
      s16x8 vf[2];
      const u16* va = vrow + (size_t)(ot * 16 + c) * (B_ * T_);
#pragma unroll
      for (int kk = 0; kk < 2; ++kk) vf[kk] = *(const s16x8*)(va + kk * 32 + quad * 8);
#pragma unroll
      for (int mi = 0; mi < 2; ++mi)
#pragma unroll
        for (int kk = 0; kk < 2; ++kk)
          of[mi][ot] = __builtin_amdgcn_mfma_f32_16x16x32_bf16(pa[mi][kk], vf[kk], of[mi][ot], 0, 0, 0);
    }
  }

  // ---- epilogue: reduce l across the 16 c-lanes sharing each row ----
#pragma unroll
  for (int mi = 0; mi < 2; ++mi)
#pragma unroll
    for (int r = 0; r < 4; ++r) {
      float v = l4[mi][r];
#pragma unroll
      for (int off = 1; off < 16; off <<= 1) v += __shfl_xor(v, off, 64);
      l4[mi][r] = v;
    }
  // merge jp=1 partials into jp=0 via f32 LDS (static max -> plain sums)
  __syncthreads();
  if (jp == 1) {
#pragma unroll
    for (int mi = 0; mi < 2; ++mi)
#pragma unroll
      for (int ot = 0; ot < 8; ++ot)
#pragma unroll
        for (int r = 0; r < 4; ++r)
          Mb[rh * 4096 + (mi * 16 + quad * 4 + r) * 128 + ot * 16 + c] = of[mi][ot][r];
    if (c == 0)
#pragma unroll
      for (int mi = 0; mi < 2; ++mi)
#pragma unroll
        for (int r = 0; r < 4; ++r)
          Mb[8192 + rh * 32 + mi * 16 + quad * 4 + r] = l4[mi][r];
  }
  __syncthreads();
  if (jp == 0) {
    u16* obase = O + ((size_t)(b * T_ + q0 + rh * 32) * H_ + h) * HD_;
#pragma unroll
    for (int mi = 0; mi < 2; ++mi) {
      float inv[4];
#pragma unroll
      for (int r = 0; r < 4; ++r)
        inv[r] = 1.0f / (l4[mi][r] + Mb[8192 + rh * 32 + mi * 16 + quad * 4 + r]);
#pragma unroll
      for (int ot = 0; ot < 8; ++ot)
#pragma unroll
        for (int r = 0; r < 4; ++r) {
          float v = of[mi][ot][r] + Mb[rh * 4096 + (mi * 16 + quad * 4 + r) * 128 + ot * 16 + c];
          obase[(size_t)(mi * 16 + quad * 4 + r) * KVSTRIDE_ + ot * 16 + c] = f2bf(v * inv[r]);
        }
    }
  }
}

// ---------------- launch ----------------
extern "C" void kernel_launch(void* const* d_in, const int* in_sizes, int n_in,
                              void* d_out, int out_size, void* d_ws, size_t ws_size,
                              hipStream_t stream) {
  const float* x = (const float*)d_in[0];
  const float* Wq = (const float*)d_in[1];
  const float* Wk = (const float*)d_in[2];
  const float* Wv = (const float*)d_in[3];
  const float* Wo = (const float*)d_in[4];
  const float* qw = (const float*)d_in[5];
  const float* kw = (const float*)d_in[6];
  float* out = (float*)d_out;

  const size_t xE = (size_t)B_ * T_ * D_;   // 8388608
  const size_t wE = (size_t)D_ * H_ * HD_;  // 4194304
  const size_t need = xE * 2 * 5 + wE * 2 * 4;  // ~112 MB
  if (ws_size < need) return;

  char* ws = (char*)d_ws;
  u16* xb = (u16*)ws;   ws += xE * 2;
  u16* wqb = (u16*)ws;  ws += wE * 2;
  u16* wkb = (u16*)ws;  ws += wE * 2;
  u16* wvb = (u16*)ws;  ws += wE * 2;
  u16* wob = (u16*)ws;  ws += wE * 2;
  u16* qb = (u16*)ws;   ws += xE * 2;
  u16* kb = (u16*)ws;   ws += xE * 2;
  u16* vtb = (u16*)ws;  ws += xE * 2;   // V^T: [H*HD][B*T]
  u16* ctxb = (u16*)ws; ws += xE * 2;

  cvt_f32_bf16<<<xE / 1024, 256, 0, stream>>>(x, xb, (int)(xE / 4));
  cvt_f32_bf16<<<wE / 1024, 256, 0, stream>>>(Wq, wqb, (int)(wE / 4));
  cvt_f32_bf16<<<wE / 1024, 256, 0, stream>>>(Wk, wkb, (int)(wE / 4));
  cvt_f32_bf16<<<wE / 1024, 256, 0, stream>>>(Wv, wvb, (int)(wE / 4));
  cvt_f32_bf16<<<wE / 1024, 256, 0, stream>>>(Wo, wob, (int)(wE / 4));

  dim3 gg(16, 32);  // (N/128, M/128)
  gemm_btn<1><<<gg, 256, 0, stream>>>(xb, wqb, qb, 4096, 2048, 2048);
  gemm_btn<1><<<gg, 256, 0, stream>>>(xb, wkb, kb, 4096, 2048, 2048);
  // V^T = Wv * x^T : M=2048 (o), N=4096 (tokens)
  dim3 ggv(32, 16);
  gemm_btn<1><<<ggv, 256, 0, stream>>>(wvb, xb, vtb, 2048, 4096, 2048);

  rmsnorm_rope<<<16384, 256, 0, stream>>>(qb, qw, QSCALE_);
  rmsnorm_rope<<<16384, 256, 0, stream>>>(kb, kw, 1.0f);

  attn_fwd<<<1024, 256, 0, stream>>>(qb, kb, vtb, ctxb);

  gemm_btn<0><<<gg, 256, 0, stream>>>(ctxb, wob, out, 4096, 2048, 2048);
}

// Round 5
// 420.209 us; speedup vs baseline: 1.2318x; 1.1640x over previous
//
#include <hip/hip_runtime.h>
#include <cstdint>
#include <cstddef>

#define B_ 2
#define T_ 2048
#define D_ 2048
#define H_ 16
#define HD_ 128
#define EPS_ 1e-6f
#define QSCALE_ 0.08838834764831845f  // 1/sqrt(128)
#define KVSTRIDE_ (H_ * HD_)          // 2048 elems between consecutive t

typedef unsigned short u16;
typedef short s16x8 __attribute__((ext_vector_type(8)));
typedef float f32x4 __attribute__((ext_vector_type(4)));

__device__ __forceinline__ float bf2f(u16 h) {
  union { unsigned int u; float f; } v;
  v.u = ((unsigned int)h) << 16;
  return v.f;
}
__device__ __forceinline__ u16 f2bf(float f) {
  union { float f; unsigned int u; } v;
  v.f = f;
  unsigned int r = v.u + 0x7FFFu + ((v.u >> 16) & 1u);  // round-to-nearest-even
  return (u16)(r >> 16);
}

// async global->LDS, 16B per lane (LDS dest = wave-uniform base + lane*16)
__device__ __forceinline__ void gload16(const void* g, void* l) {
  __builtin_amdgcn_global_load_lds(
      (const __attribute__((address_space(1))) unsigned int*)g,
      (__attribute__((address_space(3))) unsigned int*)l, 16, 0, 0);
}

// ---------------- fp32 -> bf16 cast ----------------
__global__ void cvt_f32_bf16(const float* __restrict__ in, u16* __restrict__ out, int n4) {
  int i = blockIdx.x * blockDim.x + threadIdx.x;
  if (i < n4) {
    float4 v = ((const float4*)in)[i];
    ((ushort4*)out)[i] = make_ushort4(f2bf(v.x), f2bf(v.y), f2bf(v.z), f2bf(v.w));
  }
}

// ---------------- bf16 GEMM: C[M,N] = A[M,K] * Bm[N,K]^T ----------------
// m97 structure with BK=64: two 128x32 half-tiles staged per barrier period
// (LDS [kc][128][32] keeps m97's bank-verified 64B row stride; 32 MFMA/barrier,
// half the barrier-drain stalls of BK=32). LDS 32 KB total.
template <int OUT_BF16>
__global__ __launch_bounds__(256, 2) void gemm_btn(const u16* __restrict__ A,
                                                   const u16* __restrict__ Bm,
                                                   void* __restrict__ Cout,
                                                   int M, int N, int K) {
  __shared__ u16 As[2 * 128 * 32];
  __shared__ u16 Bs[2 * 128 * 32];
  const int tid = threadIdx.x;
  const int w = tid >> 6, lane = tid & 63, quad = lane >> 4, c = lane & 15;
  const int wm = w & 1, wn = w >> 1;
  const int m0 = blockIdx.y * 128, n0 = blockIdx.x * 128;

  f32x4 acc[4][4];
#pragma unroll
  for (int i = 0; i < 4; ++i)
#pragma unroll
    for (int j = 0; j < 4; ++j) acc[i][j] = (f32x4){0.f, 0.f, 0.f, 0.f};

  for (int k0 = 0; k0 < K; k0 += 64) {
    __syncthreads();
#pragma unroll
    for (int i = 0; i < 4; ++i) {
      int chunk = (w * 4 + i) * 64 + lane;   // 0..1023
      int kc = chunk >> 9;                    // half-tile select (LDS-contiguous)
      int within = chunk & 511;
      int row = within >> 2, cc = within & 3; // 128 rows x 4 8-elem chunks
      gload16(A + (size_t)(m0 + row) * K + k0 + kc * 32 + cc * 8, (void*)(As + chunk * 8));
      gload16(Bm + (size_t)(n0 + row) * K + k0 + kc * 32 + cc * 8, (void*)(Bs + chunk * 8));
    }
    __syncthreads();
#pragma unroll
    for (int kc = 0; kc < 2; ++kc) {
      s16x8 af[4], bf[4];
#pragma unroll
      for (int mi = 0; mi < 4; ++mi)
        af[mi] = *(const s16x8*)(As + kc * 4096 + (wm * 64 + mi * 16 + c) * 32 + quad * 8);
#pragma unroll
      for (int ni = 0; ni < 4; ++ni)
        bf[ni] = *(const s16x8*)(Bs + kc * 4096 + (wn * 64 + ni * 16 + c) * 32 + quad * 8);
#pragma unroll
      for (int mi = 0; mi < 4; ++mi)
#pragma unroll
        for (int ni = 0; ni < 4; ++ni)
          acc[mi][ni] = __builtin_amdgcn_mfma_f32_16x16x32_bf16(af[mi], bf[ni], acc[mi][ni], 0, 0, 0);
    }
  }

#pragma unroll
  for (int mi = 0; mi < 4; ++mi)
#pragma unroll
    for (int ni = 0; ni < 4; ++ni)
#pragma unroll
      for (int r = 0; r < 4; ++r) {
        int row = m0 + wm * 64 + mi * 16 + quad * 4 + r;
        int col = n0 + wn * 64 + ni * 16 + c;
        float v = acc[mi][ni][r];
        if (OUT_BF16)
          ((u16*)Cout)[(size_t)row * N + col] = f2bf(v);
        else
          ((float*)Cout)[(size_t)row * N + col] = v;
      }
}

// ---------------- fused RMSNorm + interleaved RoPE (in-place on bf16) ----------------
__global__ void rmsnorm_rope(u16* __restrict__ x, const float* __restrict__ nw, float outscale) {
  const int tid = threadIdx.x;
  const int w = tid >> 6, lane = tid & 63;
  const int vec = blockIdx.x * 4 + w;   // (b*T + t)*H + h
  const int t = (vec >> 4) & (T_ - 1);  // /H % T
  u16* base = x + (size_t)vec * HD_;
  unsigned int pk = *(const unsigned int*)(base + lane * 2);
  float e = bf2f((u16)(pk & 0xFFFFu));
  float o = bf2f((u16)(pk >> 16));
  float ss = e * e + o * o;
#pragma unroll
  for (int off = 1; off < 64; off <<= 1) ss += __shfl_xor(ss, off, 64);
  float rn = rsqrtf(ss * (1.0f / HD_) + EPS_);
  float we = nw[lane * 2], wo = nw[lane * 2 + 1];
  e = e * rn * we;
  o = o * rn * wo;
  float freq = expf(-(float)lane * (9.210340371976184f / 64.0f));  // 10000^(-lane/64)
  float ang = (float)t * freq;
  float sn, cs;
  sincosf(ang, &sn, &cs);
  float re = (e * cs - o * sn) * outscale;
  float ro = (e * sn + o * cs) * outscale;
  *(unsigned int*)(base + lane * 2) = ((unsigned int)f2bf(ro) << 16) | (unsigned int)f2bf(re);
}

// ---------------- causal flash attention, Br=Bc=64, bf16 MFMA (R2 known-good) ----------------
// Q scaled by 1/sqrt(HD), layout (B,T,H,HD). K layout (B,T,H,HD).
// V is TRANSPOSED: Vt[o=h*128+d][tok=b*2048+t]  (t contiguous) -> vector B-frags.
__global__ __launch_bounds__(256, 2) void attn_fwd(const u16* __restrict__ Q,
                                                   const u16* __restrict__ Kg,
                                                   const u16* __restrict__ Vt,
                                                   u16* __restrict__ O) {
  __shared__ u16 Ks[64 * 136];   // K rows (s-major, d contig), +8 pad -> 2-way
  __shared__ u16 Vts[128 * 72];  // V^T rows (d-major, s contig), +8 pad -> 2-way
  __shared__ u16 Ps[64 * 72];    // P round-trip, +8 pad
  const int tid = threadIdx.x;
  const int w = tid >> 6, lane = tid & 63, quad = lane >> 4, c = lane & 15;
  const int bid = blockIdx.x;
  const int qt = 31 - (bid >> 5);  // heavy (qt=31) blocks dispatch first
  const int h = bid & 15;
  const int b = (bid >> 4) & 1;
  const int q0 = qt * 64;

  // Q fragments, kept in registers (rows w*16+c, A-layout)
  s16x8 qf[4];
  const u16* qbase = Q + ((size_t)(b * T_ + q0 + w * 16 + c) * H_ + h) * HD_;
#pragma unroll
  for (int kk = 0; kk < 4; ++kk) qf[kk] = *(const s16x8*)(qbase + kk * 32 + quad * 8);

  f32x4 of[8];
#pragma unroll
  for (int i = 0; i < 8; ++i) of[i] = (f32x4){0.f, 0.f, 0.f, 0.f};
  float m_i[4] = {-1e30f, -1e30f, -1e30f, -1e30f};
  float l_i[4] = {0.f, 0.f, 0.f, 0.f};

  const u16* kbase = Kg + ((size_t)b * T_ * H_ + h) * HD_;
  const u16* vtbase = Vt + (size_t)(h * HD_) * (B_ * T_) + (size_t)b * T_;

  for (int j = 0; j <= qt; ++j) {
    __syncthreads();
    // stage K tile (64 rows x 128 d-contig) and Vt tile (128 rows x 64 s-contig)
    const u16* krow = kbase + (size_t)(j * 64) * KVSTRIDE_;
    const u16* vrow = vtbase + j * 64;
#pragma unroll
    for (int i = 0; i < 4; ++i) {
      int chunk = i * 256 + tid;  // 0..1023
      int krowi = chunk >> 4, kc = chunk & 15;
      *(uint4*)(&Ks[krowi * 136 + kc * 8]) =
          *(const uint4*)(krow + (size_t)krowi * KVSTRIDE_ + kc * 8);
      int vrowi = chunk >> 3, vc = chunk & 7;
      *(uint4*)(&Vts[vrowi * 72 + vc * 8]) =
          *(const uint4*)(vrow + (size_t)vrowi * (B_ * T_) + vc * 8);
    }
    __syncthreads();

    // S = Q K^T  (rows w*16+quad*4+r, cols ni*16+c)
    f32x4 sf[4];
#pragma unroll
    for (int ni = 0; ni < 4; ++ni) {
      f32x4 a = (f32x4){0.f, 0.f, 0.f, 0.f};
#pragma unroll
      for (int kk = 0; kk < 4; ++kk) {
        s16x8 bfr = *(const s16x8*)(&Ks[(ni * 16 + c) * 136 + kk * 32 + quad * 8]);
        a = __builtin_amdgcn_mfma_f32_16x16x32_bf16(qf[kk], bfr, a, 0, 0, 0);
      }
      sf[ni] = a;
    }
    // causal mask (only needed on the diagonal tile)
    if (j == qt) {
#pragma unroll
      for (int ni = 0; ni < 4; ++ni)
#pragma unroll
        for (int r = 0; r < 4; ++r) {
          int rowg = w * 16 + quad * 4 + r;
          int colg = ni * 16 + c;
          if (colg > rowg) sf[ni][r] = -1e30f;
        }
    }
    // online softmax (rows live across 16 lanes sharing `quad`)
    float mc[4];
#pragma unroll
    for (int r = 0; r < 4; ++r)
      mc[r] = fmaxf(fmaxf(sf[0][r], sf[1][r]), fmaxf(sf[2][r], sf[3][r]));
#pragma unroll
    for (int off = 1; off < 16; off <<= 1)
#pragma unroll
      for (int r = 0; r < 4; ++r) mc[r] = fmaxf(mc[r], __shfl_xor(mc[r], off, 64));
#pragma unroll
    for (int r = 0; r < 4; ++r) {
      float mnew = fmaxf(m_i[r], mc[r]);
      float alpha = __expf(m_i[r] - mnew);
      m_i[r] = mnew;
      l_i[r] *= alpha;
#pragma unroll
      for (int ot = 0; ot < 8; ++ot) of[ot][r] *= alpha;
    }
    float rs[4] = {0.f, 0.f, 0.f, 0.f};
#pragma unroll
    for (int ni = 0; ni < 4; ++ni)
#pragma unroll
      for (int r = 0; r < 4; ++r) {
        float p = __expf(sf[ni][r] - m_i[r]);
        sf[ni][r] = p;
        rs[r] += p;
      }
#pragma unroll
    for (int off = 1; off < 16; off <<= 1)
#pragma unroll
      for (int r = 0; r < 4; ++r) rs[r] += __shfl_xor(rs[r], off, 64);
#pragma unroll
    for (int r = 0; r < 4; ++r) l_i[r] += rs[r];
    // write P (C-layout -> LDS, rows w*16+quad*4+r)
#pragma unroll
    for (int ni = 0; ni < 4; ++ni)
#pragma unroll
      for (int r = 0; r < 4; ++r)
        Ps[(w * 16 + quad * 4 + r) * 72 + ni * 16 + c] = f2bf(sf[ni][r]);
    __syncthreads();
    // O += P V  (A-frag of P: rows w*16+c; B-frag of V: one ds_read_b128 from Vt)
    s16x8 pa[2];
    pa[0] = *(const s16x8*)(&Ps[(w * 16 + c) * 72 + quad * 8]);
    pa[1] = *(const s16x8*)(&Ps[(w * 16 + c) * 72 + 32 + quad * 8]);
#pragma unroll
    for (int ot = 0; ot < 8; ++ot) {
#pragma unroll
      for (int kk = 0; kk < 2; ++kk) {
        s16x8 vfr = *(const s16x8*)(&Vts[(ot * 16 + c) * 72 + kk * 32 + quad * 8]);
        of[ot] = __builtin_amdgcn_mfma_f32_16x16x32_bf16(pa[kk], vfr, of[ot], 0, 0, 0);
      }
    }
  }

  // epilogue: O /= l, store bf16 ctx (flat (B,T,H,HD) layout)
  float inv[4];
#pragma unroll
  for (int r = 0; r < 4; ++r) inv[r] = 1.0f / l_i[r];
  u16* obase = O + ((size_t)(b * T_ + q0) * H_ + h) * HD_;
#pragma unroll
  for (int ot = 0; ot < 8; ++ot)
#pragma unroll
    for (int r = 0; r < 4; ++r)
      obase[(size_t)(w * 16 + quad * 4 + r) * KVSTRIDE_ + ot * 16 + c] = f2bf(of[ot][r] * inv[r]);
}

// ---------------- launch ----------------
extern "C" void kernel_launch(void* const* d_in, const int* in_sizes, int n_in,
                              void* d_out, int out_size, void* d_ws, size_t ws_size,
                              hipStream_t stream) {
  const float* x = (const float*)d_in[0];
  const float* Wq = (const float*)d_in[1];
  const float* Wk = (const float*)d_in[2];
  const float* Wv = (const float*)d_in[3];
  const float* Wo = (const float*)d_in[4];
  const float* qw = (const float*)d_in[5];
  const float* kw = (const float*)d_in[6];
  float* out = (float*)d_out;

  const size_t xE = (size_t)B_ * T_ * D_;   // 8388608
  const size_t wE = (size_t)D_ * H_ * HD_;  // 4194304
  const size_t need = xE * 2 * 5 + wE * 2 * 4;  // ~112 MB
  if (ws_size < need) return;

  char* ws = (char*)d_ws;
  u16* xb = (u16*)ws;   ws += xE * 2;
  u16* wqb = (u16*)ws;  ws += wE * 2;
  u16* wkb = (u16*)ws;  ws += wE * 2;
  u16* wvb = (u16*)ws;  ws += wE * 2;
  u16* wob = (u16*)ws;  ws += wE * 2;
  u16* qb = (u16*)ws;   ws += xE * 2;
  u16* kb = (u16*)ws;   ws += xE * 2;
  u16* vtb = (u16*)ws;  ws += xE * 2;   // V^T: [H*HD][B*T]
  u16* ctxb = (u16*)ws; ws += xE * 2;

  cvt_f32_bf16<<<xE / 1024, 256, 0, stream>>>(x, xb, (int)(xE / 4));
  cvt_f32_bf16<<<wE / 1024, 256, 0, stream>>>(Wq, wqb, (int)(wE / 4));
  cvt_f32_bf16<<<wE / 1024, 256, 0, stream>>>(Wk, wkb, (int)(wE / 4));
  cvt_f32_bf16<<<wE / 1024, 256, 0, stream>>>(Wv, wvb, (int)(wE / 4));
  cvt_f32_bf16<<<wE / 1024, 256, 0, stream>>>(Wo, wob, (int)(wE / 4));

  dim3 gg(16, 32);  // (N/128, M/128)
  gemm_btn<1><<<gg, 256, 0, stream>>>(xb, wqb, qb, 4096, 2048, 2048);
  gemm_btn<1><<<gg, 256, 0, stream>>>(xb, wkb, kb, 4096, 2048, 2048);
  // V^T = Wv * x^T : M=2048 (o), N=4096 (tokens)
  dim3 ggv(32, 16);
  gemm_btn<1><<<ggv, 256, 0, stream>>>(wvb, xb, vtb, 2048, 4096, 2048);

  rmsnorm_rope<<<16384, 256, 0, stream>>>(qb, qw, QSCALE_);
  rmsnorm_rope<<<16384, 256, 0, stream>>>(kb, kw, 1.0f);

  attn_fwd<<<B_ * H_ * (T_ / 64), 256, 0, stream>>>(qb, kb, vtb, ctxb);

  gemm_btn<0><<<gg, 256, 0, stream>>>(ctxb, wob, out, 4096, 2048, 2048);
}